// Round 2
// baseline (255.043 us; speedup 1.0000x reference)
//
#include <hip/hip_runtime.h>
#include <math.h>

#define NSITES 100000
#define NYEARS 20
#define HDIM 64
#define WSTR 72   // LDS weight row stride (bf16 elems); 144B, 16B-aligned

typedef __bf16 bf16x8 __attribute__((ext_vector_type(8)));
typedef float f32x4 __attribute__((ext_vector_type(4)));

__device__ __forceinline__ float sigmoidf_(float x) { return 1.0f / (1.0f + __expf(-x)); }
// fast elu: __expf(x)-1 instead of expm1f (libm expm1f is ~25 instrs; error ~1e-7,
// far below harness tolerance 1.85e-2, and result is bf16-truncated downstream anyway)
__device__ __forceinline__ float eluf_(float x) { return x > 0.0f ? x : __expf(x) - 1.0f; }

__device__ __forceinline__ unsigned pack2_(float a, float b) {
    union { __bf16 h; unsigned short u; } x, y;
    x.h = (__bf16)a; y.h = (__bf16)b;
    return ((unsigned)y.u << 16) | (unsigned)x.u;
}

// load 8 consecutive f32 (32B-aligned) -> bf16x8
__device__ __forceinline__ bf16x8 cvt8_(const float* p) {
    float4 a = ((const float4*)p)[0];
    float4 b = ((const float4*)p)[1];
    bf16x8 r;
    r[0] = (__bf16)a.x; r[1] = (__bf16)a.y; r[2] = (__bf16)a.z; r[3] = (__bf16)a.w;
    r[4] = (__bf16)b.x; r[5] = (__bf16)b.y; r[6] = (__bf16)b.z; r[7] = (__bf16)b.w;
    return r;
}

// read 8 bf16 (16B) from LDS weight tile at (row, col off)
__device__ __forceinline__ bf16x8 ldsfrag_(const unsigned short* b, int row, int off) {
    union { bf16x8 v; uint4 u; } r;
    r.u = *(const uint4*)&b[row * WSTR + off];
    return r.v;
}

__device__ __forceinline__ bf16x8 pack_bf_(f32x4 lo, f32x4 hi) {
    bf16x8 r;
    r[0] = (__bf16)lo[0]; r[1] = (__bf16)lo[1]; r[2] = (__bf16)lo[2]; r[3] = (__bf16)lo[3];
    r[4] = (__bf16)hi[0]; r[5] = (__bf16)hi[1]; r[6] = (__bf16)hi[2]; r[7] = (__bf16)hi[3];
    return r;
}

// 256-thread block = 4 waves x 16 sites (64 sites/block, 1563 blocks).
// R14 = R13 with the psi slot off-by-one fixed. R13's overlay was sound
// (psi0 passed); the bug was writing psi(h_{t-1}) to slot t instead of t-1,
// shifting the whole psi output by one year.
//
// LDS overlay (the R13 occupancy lever, kept): logits (10.2KB: pL + psiL,
// psi0 folded into psiL slot 0 by overwriting the dead psi(h_0) value at t=1)
// live on the COMBINED 18.4KB weight region. Weights are dead after the
// pre-loop a_hh/h0 register loads; an explicit __syncthreads() separates the
// last cross-wave weight read from the first logit write.
// LDS 33792 -> 23296 B: 6+ blocks/CU (was ~2: Occ 26%, VALUBusy 50%,
// latency-starved serial recurrence).
//
// Loop body = validated R8/R10: rolled t-loop, permuted-output-row MFMA
// recurrence pi(32kt+8q+4b+r)=16(2kt+b)+4q+r (lane's D regs ARE its next-round
// B-fragment), heads as 5th m-tile, xs pipelined.
// Slot semantics (accH at round t is computed from bf = h_{t-1}):
//   pL[sl*20 + k]   = p-logit(h_k),   k=0..19 (19 from final-heads block)
//   psiL[sl*20 + k] = psi-logit(h_k), k=1..19; slot 0 = psi0-logit(h0)
__global__ __launch_bounds__(256, 6)
void rnet_kernel(const float* __restrict__ sxy0,
                 const float* __restrict__ sxy,
                 const float* __restrict__ oxy,
                 const float* __restrict__ W_h0, const float* __restrict__ b_h0,
                 const float* __restrict__ W_h1, const float* __restrict__ b_h1,
                 const float* __restrict__ W_ih, const float* __restrict__ b_ih,
                 const float* __restrict__ W_hh, const float* __restrict__ b_hh,
                 const float* __restrict__ W_psi0, const float* __restrict__ b_psi0,
                 const float* __restrict__ W_psi, const float* __restrict__ b_psi,
                 const float* __restrict__ W_p, const float* __restrict__ b_p,
                 float* __restrict__ out)
{
    const int tid  = threadIdx.x;       // 0..255
    const int lane = tid & 63;
    const int wv   = tid >> 6;          // wave 0..3
    const int s = lane & 15;            // site within wave / A-row within tile
    const int q = lane >> 4;            // quad
    const int sq = s >> 2, sr = s & 3;
    const int base = blockIdx.x * 64;   // 1563 blocks; last block partial
    const int sl   = wv * 16 + s;       // site local 0..63
    const int site = base + sl;
    const int site_ld = site < NSITES ? site : NSITES - 1;   // clamped for loads

    // ==== LDS: weight region (18432 B) later overlaid by logit buffers (10240 B) ====
    __shared__ __align__(16) unsigned short wbuf[2 * 64 * WSTR]; // whh | wh1
    __shared__ __align__(16) float xs_sh[64 * 19];
    unsigned short* const whh_l = wbuf;                 // bf16 W_hh [64][WSTR]
    unsigned short* const wh1_l = wbuf + 64 * WSTR;     // bf16 W_h1 [64][WSTR]
    float* const pL   = (float*)wbuf;                   // [64][20] raw p logits (overlay)
    float* const psiL = (float*)wbuf + 64 * 20;         // [64][20]; slot0 = psi0 logit

    float* __restrict__ out_psi0 = out;                 // [N]
    float* __restrict__ out_psi  = out + NSITES;        // [N,19]
    float* __restrict__ out_p    = out + 20 * NSITES;   // [N,20,2]

    // ==== stage weights (coalesced f32->bf16) + xs into LDS ====
    {
        const float4* whg = (const float4*)W_hh;
        const float4* w1g = (const float4*)W_h1;
#pragma unroll
        for (int j = 0; j < 4; ++j) {
            int e4 = j * 256 + tid;            // 0..1023 (1024 float4 = 64x64)
            int row = e4 >> 4, c4 = e4 & 15;
            float4 a = whg[e4];
            uint2 pa; pa.x = pack2_(a.x, a.y); pa.y = pack2_(a.z, a.w);
            *(uint2*)&whh_l[row * WSTR + c4 * 4] = pa;
            float4 b = w1g[e4];
            uint2 pb; pb.x = pack2_(b.x, b.y); pb.y = pack2_(b.z, b.w);
            *(uint2*)&wh1_l[row * WSTR + c4 * 4] = pb;
        }
        // xs: 64*19 = 1216 floats; clamp per-site row for tail block
#pragma unroll
        for (int r = 0; r < 5; ++r) {
            int i = r * 256 + tid;
            if (i < 64 * 19) {
                int srow = i / 19, c = i - srow * 19;
                int gsite = base + srow; if (gsite >= NSITES) gsite = NSITES - 1;
                xs_sh[i] = sxy[(size_t)gsite * 19 + c];
            }
        }
    }
    __syncthreads();

    // ==== h0 stage: hs = elu(s0*W_h0+b_h0) in B layout; h0 via permuted W_h1 (LDS) ====
    bf16x8 bf[2];
    {
        const float s0v = sxy0[site_ld];
        bf16x8 bf0[2];
#pragma unroll
        for (int kt = 0; kt < 2; ++kt) {
            const float* wp = W_h0 + kt * 32 + q * 8;
            const float* bp = b_h0 + kt * 32 + q * 8;
            float4 w0 = ((const float4*)wp)[0], w1 = ((const float4*)wp)[1];
            float4 c0 = ((const float4*)bp)[0], c1 = ((const float4*)bp)[1];
            float v[8];
            v[0] = eluf_(fmaf(s0v, w0.x, c0.x)); v[1] = eluf_(fmaf(s0v, w0.y, c0.y));
            v[2] = eluf_(fmaf(s0v, w0.z, c0.z)); v[3] = eluf_(fmaf(s0v, w0.w, c0.w));
            v[4] = eluf_(fmaf(s0v, w1.x, c1.x)); v[5] = eluf_(fmaf(s0v, w1.y, c1.y));
            v[6] = eluf_(fmaf(s0v, w1.z, c1.z)); v[7] = eluf_(fmaf(s0v, w1.w, c1.w));
#pragma unroll
            for (int j = 0; j < 8; ++j) bf0[kt][j] = (__bf16)v[j];
        }

        f32x4 acc[4];
#pragma unroll
        for (int mt = 0; mt < 4; ++mt) {
            const int dr = 32 * (mt >> 1) + 8 * q + 4 * (mt & 1);
            float4 b1 = *(const float4*)(b_h1 + dr);
            acc[mt][0] = b1.x; acc[mt][1] = b1.y; acc[mt][2] = b1.z; acc[mt][3] = b1.w;
        }
#pragma unroll
        for (int kt = 0; kt < 2; ++kt)
#pragma unroll
            for (int mt = 0; mt < 4; ++mt) {
                const int ar = 32 * (mt >> 1) + 8 * sq + 4 * (mt & 1) + sr;
                bf16x8 a = ldsfrag_(wh1_l, ar, kt * 32 + q * 8);
                acc[mt] = __builtin_amdgcn_mfma_f32_16x16x32_bf16(a, bf0[kt], acc[mt], 0, 0, 0);
            }
        f32x4 e[4];
#pragma unroll
        for (int mt = 0; mt < 4; ++mt)
#pragma unroll
            for (int r = 0; r < 4; ++r) e[mt][r] = eluf_(acc[mt][r]);
        bf[0] = pack_bf_(e[0], e[1]);
        bf[1] = pack_bf_(e[2], e[3]);
    }

    // ==== persistent loop state: a_hh from LDS, small stuff direct ====
    bf16x8 a_hh[4][2];
#pragma unroll
    for (int mt = 0; mt < 4; ++mt) {
        const int ar = 32 * (mt >> 1) + 8 * sq + 4 * (mt & 1) + sr;
#pragma unroll
        for (int kt = 0; kt < 2; ++kt)
            a_hh[mt][kt] = ldsfrag_(whh_l, ar, kt * 32 + q * 8);
    }

    // ALL cross-wave LDS weight reads are now done (each wave read wh1_l in its
    // h0 stage and whh_l just above). Barrier before any wave may overwrite the
    // weight region with logits inside the t-loop.
    __syncthreads();

    bf16x8 a_head[2];
    {
        const float* hrow = (s == 1) ? W_p : ((s == 2) ? W_psi0 : W_psi);
#pragma unroll
        for (int kt = 0; kt < 2; ++kt) a_head[kt] = cvt8_(hrow + kt * 32 + q * 8);
    }
    f32x4 biasD[4], wihD[4];
#pragma unroll
    for (int mt = 0; mt < 4; ++mt) {
        const int dr = 32 * (mt >> 1) + 8 * q + 4 * (mt & 1);
        float4 bi = *(const float4*)(b_ih + dr);
        float4 bh = *(const float4*)(b_hh + dr);
        float4 wi = *(const float4*)(W_ih + dr);
        biasD[mt][0] = bi.x + bh.x; biasD[mt][1] = bi.y + bh.y;
        biasD[mt][2] = bi.z + bh.z; biasD[mt][3] = bi.w + bh.w;
        wihD[mt][0] = wi.x; wihD[mt][1] = wi.y; wihD[mt][2] = wi.z; wihD[mt][3] = wi.w;
    }
    f32x4 headC;
    headC[0] = (q == 0) ? b_psi[0]  : 0.0f;
    headC[1] = (q == 0) ? b_p[0]    : 0.0f;
    headC[2] = (q == 0) ? b_psi0[0] : 0.0f;
    headC[3] = 0.0f;

    // ==== recurrence: ROLLED, xs read pipelined one round ahead ====
    float x = xs_sh[sl * 19];          // x for round t=1
#pragma unroll 1
    for (int t = 1; t < NYEARS; ++t) {
        float x_next = (t < NYEARS - 1) ? xs_sh[sl * 19 + t] : 0.0f;

        f32x4 acc[4], accH;
#pragma unroll
        for (int mt = 0; mt < 4; ++mt)
            acc[mt] = __builtin_amdgcn_mfma_f32_16x16x32_bf16(a_hh[mt][0], bf[0], biasD[mt], 0, 0, 0);
        accH = __builtin_amdgcn_mfma_f32_16x16x32_bf16(a_head[0], bf[0], headC, 0, 0, 0);
#pragma unroll
        for (int mt = 0; mt < 4; ++mt)
            acc[mt] = __builtin_amdgcn_mfma_f32_16x16x32_bf16(a_hh[mt][1], bf[1], acc[mt], 0, 0, 0);
        accH = __builtin_amdgcn_mfma_f32_16x16x32_bf16(a_head[1], bf[1], accH, 0, 0, 0);

        f32x4 hn[4];
#pragma unroll
        for (int mt = 0; mt < 4; ++mt)
#pragma unroll
            for (int r = 0; r < 4; ++r)
                hn[mt][r] = fmaxf(fmaf(x, wihD[mt][r], acc[mt][r]), 0.0f);
        bf[0] = pack_bf_(hn[0], hn[1]);
        bf[1] = pack_bf_(hn[2], hn[3]);

        if (q == 0) {
            // accH is from bf = h_{t-1}: slot (t-1) semantics (R12-validated).
            pL[sl * 20 + (t - 1)]   = accH[1];   // p-logit(h_{t-1}), slots 0..18
            psiL[sl * 20 + (t - 1)] = accH[0];   // psi-logit(h_{t-1}); slot 0 is dead
            if (t == 1) psiL[sl * 20] = accH[2]; // overwrite dead slot 0 with psi0-logit
        }
        x = x_next;
    }

    // ==== final heads on h_19 ====
    {
        f32x4 accH = __builtin_amdgcn_mfma_f32_16x16x32_bf16(a_head[0], bf[0], headC, 0, 0, 0);
        accH = __builtin_amdgcn_mfma_f32_16x16x32_bf16(a_head[1], bf[1], accH, 0, 0, 0);
        if (q == 0) {
            pL[sl * 20 + 19]   = accH[1];   // p-logit(h_19)
            psiL[sl * 20 + 19] = accH[0];   // psi-logit(h_19)
        }
    }

    __syncthreads();

    // ==== epilogue: sigmoid + oxy, 256 threads over 64 sites, guarded ====
    const float wpo = W_p[HDIM];
    if (tid < 64 && base + tid < NSITES) out_psi0[base + tid] = sigmoidf_(psiL[tid * 20]);
    // psi: 64*19 = 1216; out flat i = sl*19 + c <- psiL[sl*20 + c+1]
#pragma unroll
    for (int r = 0; r < 5; ++r) {
        int i = r * 256 + tid;
        if (i < 64 * 19 && (size_t)base * 19 + i < (size_t)NSITES * 19) {
            int s2 = i / 19, c = i - s2 * 19;
            out_psi[(size_t)base * 19 + i] = sigmoidf_(psiL[s2 * 20 + c + 1]);
        }
    }
    // p: 64*40 = 2560 floats = 640 float4; float idx f -> logit pL[f>>1]
    const float4* oxy_b = (const float4*)(oxy + (size_t)base * 40);
    float4* outp_b = (float4*)(out_p + (size_t)base * 40);
    const int p4max = (NSITES * 40) / 4;   // global float4 bound
#pragma unroll
    for (int r = 0; r < 3; ++r) {
        int i4 = r * 256 + tid;
        if (i4 < 640 && blockIdx.x * 640 + i4 < p4max) {
            float4 ox = oxy_b[i4];
            float lg0 = pL[i4 * 2];
            float lg1 = pL[i4 * 2 + 1];
            float4 pv;
            pv.x = sigmoidf_(fmaf(wpo, ox.x, lg0));
            pv.y = sigmoidf_(fmaf(wpo, ox.y, lg0));
            pv.z = sigmoidf_(fmaf(wpo, ox.z, lg1));
            pv.w = sigmoidf_(fmaf(wpo, ox.w, lg1));
            outp_b[i4] = pv;
        }
    }
}

extern "C" void kernel_launch(void* const* d_in, const int* in_sizes, int n_in,
                              void* d_out, int out_size, void* d_ws, size_t ws_size,
                              hipStream_t stream) {
    const float* sxy0   = (const float*)d_in[0];
    const float* sxy    = (const float*)d_in[1];
    const float* oxy    = (const float*)d_in[2];
    const float* W_h0   = (const float*)d_in[3];
    const float* b_h0   = (const float*)d_in[4];
    const float* W_h1   = (const float*)d_in[5];
    const float* b_h1   = (const float*)d_in[6];
    const float* W_ih   = (const float*)d_in[7];
    const float* b_ih   = (const float*)d_in[8];
    const float* W_hh   = (const float*)d_in[9];
    const float* b_hh   = (const float*)d_in[10];
    const float* W_psi0 = (const float*)d_in[11];
    const float* b_psi0 = (const float*)d_in[12];
    const float* W_psi  = (const float*)d_in[13];
    const float* b_psi  = (const float*)d_in[14];
    const float* W_p    = (const float*)d_in[15];
    const float* b_p    = (const float*)d_in[16];

    float* out = (float*)d_out;

    dim3 block(256);
    dim3 grid((NSITES + 63) / 64);   // 1563 blocks, 4 waves x 16 sites each
    rnet_kernel<<<grid, block, 0, stream>>>(
        sxy0, sxy, oxy, W_h0, b_h0, W_h1, b_h1, W_ih, b_ih, W_hh, b_hh,
        W_psi0, b_psi0, W_psi, b_psi, W_p, b_p, out);
}

// Round 3
// 137.640 us; speedup vs baseline: 1.8530x; 1.8530x over previous
//
#include <hip/hip_runtime.h>
#include <math.h>

#define NSITES 100000
#define NYEARS 20
#define HDIM 64
#define WSTR 72   // LDS weight row stride (bf16 elems); 144B, 16B-aligned

typedef __bf16 bf16x8 __attribute__((ext_vector_type(8)));
typedef float f32x4 __attribute__((ext_vector_type(4)));

__device__ __forceinline__ float sigmoidf_(float x) { return 1.0f / (1.0f + __expf(-x)); }
// fast elu: __expf(x)-1 instead of expm1f (error ~1e-7, far below tolerance,
// and result is bf16-truncated downstream anyway)
__device__ __forceinline__ float eluf_(float x) { return x > 0.0f ? x : __expf(x) - 1.0f; }

__device__ __forceinline__ unsigned pack2_(float a, float b) {
    union { __bf16 h; unsigned short u; } x, y;
    x.h = (__bf16)a; y.h = (__bf16)b;
    return ((unsigned)y.u << 16) | (unsigned)x.u;
}

// load 8 consecutive f32 (32B-aligned) -> bf16x8
__device__ __forceinline__ bf16x8 cvt8_(const float* p) {
    float4 a = ((const float4*)p)[0];
    float4 b = ((const float4*)p)[1];
    bf16x8 r;
    r[0] = (__bf16)a.x; r[1] = (__bf16)a.y; r[2] = (__bf16)a.z; r[3] = (__bf16)a.w;
    r[4] = (__bf16)b.x; r[5] = (__bf16)b.y; r[6] = (__bf16)b.z; r[7] = (__bf16)b.w;
    return r;
}

// read 8 bf16 (16B) from LDS weight tile at (row, col off)
__device__ __forceinline__ bf16x8 ldsfrag_(const unsigned short* b, int row, int off) {
    union { bf16x8 v; uint4 u; } r;
    r.u = *(const uint4*)&b[row * WSTR + off];
    return r.v;
}

__device__ __forceinline__ bf16x8 pack_bf_(f32x4 lo, f32x4 hi) {
    bf16x8 r;
    r[0] = (__bf16)lo[0]; r[1] = (__bf16)lo[1]; r[2] = (__bf16)lo[2]; r[3] = (__bf16)lo[3];
    r[4] = (__bf16)hi[0]; r[5] = (__bf16)hi[1]; r[6] = (__bf16)hi[2]; r[7] = (__bf16)hi[3];
    return r;
}

// 256-thread block = 4 waves x 16 sites (64 sites/block, 1563 blocks).
// R15 = R14 with launch_bounds reverted to (256, 2) — R14's (256, 6) capped
// the allocator at 40 VGPRs, below the ~64 VGPRs of live loop state, causing
// scratch spill in the 19-iter t-loop: FETCH 12->265 MB, WRITE 23->135 MB,
// VALUBusy 50->10%, dur 45->167us. (256,2) was R12-verified: VGPR=64, 0 spill.
//
// LDS overlay (R14-validated, kept): logits (10.2KB: pL + psiL, psi0 folded
// into psiL slot 0 by overwriting the dead psi(h_0) value at t=1) live on the
// COMBINED 18.4KB weight region. Weights are dead after the pre-loop a_hh/h0
// register loads; an explicit __syncthreads() separates the last cross-wave
// weight read from the first logit write. LDS 33792 -> 23552 B: 6 blocks/CU
// (LDS-limited; VGPR=64 allows 8). Grid is 6.1 blocks/CU of work -> nearly
// fully co-resident.
//
// Loop body = validated R8/R10: rolled t-loop, permuted-output-row MFMA
// recurrence pi(32kt+8q+4b+r)=16(2kt+b)+4q+r (lane's D regs ARE its next-round
// B-fragment), heads as 5th m-tile, xs pipelined.
// Slot semantics (accH at round t is computed from bf = h_{t-1}):
//   pL[sl*20 + k]   = p-logit(h_k),   k=0..19 (19 from final-heads block)
//   psiL[sl*20 + k] = psi-logit(h_k), k=1..19; slot 0 = psi0-logit(h0)
__global__ __launch_bounds__(256, 2)
void rnet_kernel(const float* __restrict__ sxy0,
                 const float* __restrict__ sxy,
                 const float* __restrict__ oxy,
                 const float* __restrict__ W_h0, const float* __restrict__ b_h0,
                 const float* __restrict__ W_h1, const float* __restrict__ b_h1,
                 const float* __restrict__ W_ih, const float* __restrict__ b_ih,
                 const float* __restrict__ W_hh, const float* __restrict__ b_hh,
                 const float* __restrict__ W_psi0, const float* __restrict__ b_psi0,
                 const float* __restrict__ W_psi, const float* __restrict__ b_psi,
                 const float* __restrict__ W_p, const float* __restrict__ b_p,
                 float* __restrict__ out)
{
    const int tid  = threadIdx.x;       // 0..255
    const int lane = tid & 63;
    const int wv   = tid >> 6;          // wave 0..3
    const int s = lane & 15;            // site within wave / A-row within tile
    const int q = lane >> 4;            // quad
    const int sq = s >> 2, sr = s & 3;
    const int base = blockIdx.x * 64;   // 1563 blocks; last block partial
    const int sl   = wv * 16 + s;       // site local 0..63
    const int site = base + sl;
    const int site_ld = site < NSITES ? site : NSITES - 1;   // clamped for loads

    // ==== LDS: weight region (18432 B) later overlaid by logit buffers (10240 B) ====
    __shared__ __align__(16) unsigned short wbuf[2 * 64 * WSTR]; // whh | wh1
    __shared__ __align__(16) float xs_sh[64 * 19];
    unsigned short* const whh_l = wbuf;                 // bf16 W_hh [64][WSTR]
    unsigned short* const wh1_l = wbuf + 64 * WSTR;     // bf16 W_h1 [64][WSTR]
    float* const pL   = (float*)wbuf;                   // [64][20] raw p logits (overlay)
    float* const psiL = (float*)wbuf + 64 * 20;         // [64][20]; slot0 = psi0 logit

    float* __restrict__ out_psi0 = out;                 // [N]
    float* __restrict__ out_psi  = out + NSITES;        // [N,19]
    float* __restrict__ out_p    = out + 20 * NSITES;   // [N,20,2]

    // ==== stage weights (coalesced f32->bf16) + xs into LDS ====
    {
        const float4* whg = (const float4*)W_hh;
        const float4* w1g = (const float4*)W_h1;
#pragma unroll
        for (int j = 0; j < 4; ++j) {
            int e4 = j * 256 + tid;            // 0..1023 (1024 float4 = 64x64)
            int row = e4 >> 4, c4 = e4 & 15;
            float4 a = whg[e4];
            uint2 pa; pa.x = pack2_(a.x, a.y); pa.y = pack2_(a.z, a.w);
            *(uint2*)&whh_l[row * WSTR + c4 * 4] = pa;
            float4 b = w1g[e4];
            uint2 pb; pb.x = pack2_(b.x, b.y); pb.y = pack2_(b.z, b.w);
            *(uint2*)&wh1_l[row * WSTR + c4 * 4] = pb;
        }
        // xs: 64*19 = 1216 floats; clamp per-site row for tail block
#pragma unroll
        for (int r = 0; r < 5; ++r) {
            int i = r * 256 + tid;
            if (i < 64 * 19) {
                int srow = i / 19, c = i - srow * 19;
                int gsite = base + srow; if (gsite >= NSITES) gsite = NSITES - 1;
                xs_sh[i] = sxy[(size_t)gsite * 19 + c];
            }
        }
    }
    __syncthreads();

    // ==== h0 stage: hs = elu(s0*W_h0+b_h0) in B layout; h0 via permuted W_h1 (LDS) ====
    bf16x8 bf[2];
    {
        const float s0v = sxy0[site_ld];
        bf16x8 bf0[2];
#pragma unroll
        for (int kt = 0; kt < 2; ++kt) {
            const float* wp = W_h0 + kt * 32 + q * 8;
            const float* bp = b_h0 + kt * 32 + q * 8;
            float4 w0 = ((const float4*)wp)[0], w1 = ((const float4*)wp)[1];
            float4 c0 = ((const float4*)bp)[0], c1 = ((const float4*)bp)[1];
            float v[8];
            v[0] = eluf_(fmaf(s0v, w0.x, c0.x)); v[1] = eluf_(fmaf(s0v, w0.y, c0.y));
            v[2] = eluf_(fmaf(s0v, w0.z, c0.z)); v[3] = eluf_(fmaf(s0v, w0.w, c0.w));
            v[4] = eluf_(fmaf(s0v, w1.x, c1.x)); v[5] = eluf_(fmaf(s0v, w1.y, c1.y));
            v[6] = eluf_(fmaf(s0v, w1.z, c1.z)); v[7] = eluf_(fmaf(s0v, w1.w, c1.w));
#pragma unroll
            for (int j = 0; j < 8; ++j) bf0[kt][j] = (__bf16)v[j];
        }

        f32x4 acc[4];
#pragma unroll
        for (int mt = 0; mt < 4; ++mt) {
            const int dr = 32 * (mt >> 1) + 8 * q + 4 * (mt & 1);
            float4 b1 = *(const float4*)(b_h1 + dr);
            acc[mt][0] = b1.x; acc[mt][1] = b1.y; acc[mt][2] = b1.z; acc[mt][3] = b1.w;
        }
#pragma unroll
        for (int kt = 0; kt < 2; ++kt)
#pragma unroll
            for (int mt = 0; mt < 4; ++mt) {
                const int ar = 32 * (mt >> 1) + 8 * sq + 4 * (mt & 1) + sr;
                bf16x8 a = ldsfrag_(wh1_l, ar, kt * 32 + q * 8);
                acc[mt] = __builtin_amdgcn_mfma_f32_16x16x32_bf16(a, bf0[kt], acc[mt], 0, 0, 0);
            }
        f32x4 e[4];
#pragma unroll
        for (int mt = 0; mt < 4; ++mt)
#pragma unroll
            for (int r = 0; r < 4; ++r) e[mt][r] = eluf_(acc[mt][r]);
        bf[0] = pack_bf_(e[0], e[1]);
        bf[1] = pack_bf_(e[2], e[3]);
    }

    // ==== persistent loop state: a_hh from LDS, small stuff direct ====
    bf16x8 a_hh[4][2];
#pragma unroll
    for (int mt = 0; mt < 4; ++mt) {
        const int ar = 32 * (mt >> 1) + 8 * sq + 4 * (mt & 1) + sr;
#pragma unroll
        for (int kt = 0; kt < 2; ++kt)
            a_hh[mt][kt] = ldsfrag_(whh_l, ar, kt * 32 + q * 8);
    }

    // ALL cross-wave LDS weight reads are now done (each wave read wh1_l in its
    // h0 stage and whh_l just above). Barrier before any wave may overwrite the
    // weight region with logits inside the t-loop.
    __syncthreads();

    bf16x8 a_head[2];
    {
        const float* hrow = (s == 1) ? W_p : ((s == 2) ? W_psi0 : W_psi);
#pragma unroll
        for (int kt = 0; kt < 2; ++kt) a_head[kt] = cvt8_(hrow + kt * 32 + q * 8);
    }
    f32x4 biasD[4], wihD[4];
#pragma unroll
    for (int mt = 0; mt < 4; ++mt) {
        const int dr = 32 * (mt >> 1) + 8 * q + 4 * (mt & 1);
        float4 bi = *(const float4*)(b_ih + dr);
        float4 bh = *(const float4*)(b_hh + dr);
        float4 wi = *(const float4*)(W_ih + dr);
        biasD[mt][0] = bi.x + bh.x; biasD[mt][1] = bi.y + bh.y;
        biasD[mt][2] = bi.z + bh.z; biasD[mt][3] = bi.w + bh.w;
        wihD[mt][0] = wi.x; wihD[mt][1] = wi.y; wihD[mt][2] = wi.z; wihD[mt][3] = wi.w;
    }
    f32x4 headC;
    headC[0] = (q == 0) ? b_psi[0]  : 0.0f;
    headC[1] = (q == 0) ? b_p[0]    : 0.0f;
    headC[2] = (q == 0) ? b_psi0[0] : 0.0f;
    headC[3] = 0.0f;

    // ==== recurrence: ROLLED, xs read pipelined one round ahead ====
    float x = xs_sh[sl * 19];          // x for round t=1
#pragma unroll 1
    for (int t = 1; t < NYEARS; ++t) {
        float x_next = (t < NYEARS - 1) ? xs_sh[sl * 19 + t] : 0.0f;

        f32x4 acc[4], accH;
#pragma unroll
        for (int mt = 0; mt < 4; ++mt)
            acc[mt] = __builtin_amdgcn_mfma_f32_16x16x32_bf16(a_hh[mt][0], bf[0], biasD[mt], 0, 0, 0);
        accH = __builtin_amdgcn_mfma_f32_16x16x32_bf16(a_head[0], bf[0], headC, 0, 0, 0);
#pragma unroll
        for (int mt = 0; mt < 4; ++mt)
            acc[mt] = __builtin_amdgcn_mfma_f32_16x16x32_bf16(a_hh[mt][1], bf[1], acc[mt], 0, 0, 0);
        accH = __builtin_amdgcn_mfma_f32_16x16x32_bf16(a_head[1], bf[1], accH, 0, 0, 0);

        f32x4 hn[4];
#pragma unroll
        for (int mt = 0; mt < 4; ++mt)
#pragma unroll
            for (int r = 0; r < 4; ++r)
                hn[mt][r] = fmaxf(fmaf(x, wihD[mt][r], acc[mt][r]), 0.0f);
        bf[0] = pack_bf_(hn[0], hn[1]);
        bf[1] = pack_bf_(hn[2], hn[3]);

        if (q == 0) {
            // accH is from bf = h_{t-1}: slot (t-1) semantics (R12-validated).
            pL[sl * 20 + (t - 1)]   = accH[1];   // p-logit(h_{t-1}), slots 0..18
            psiL[sl * 20 + (t - 1)] = accH[0];   // psi-logit(h_{t-1}); slot 0 is dead
            if (t == 1) psiL[sl * 20] = accH[2]; // overwrite dead slot 0 with psi0-logit
        }
        x = x_next;
    }

    // ==== final heads on h_19 ====
    {
        f32x4 accH = __builtin_amdgcn_mfma_f32_16x16x32_bf16(a_head[0], bf[0], headC, 0, 0, 0);
        accH = __builtin_amdgcn_mfma_f32_16x16x32_bf16(a_head[1], bf[1], accH, 0, 0, 0);
        if (q == 0) {
            pL[sl * 20 + 19]   = accH[1];   // p-logit(h_19)
            psiL[sl * 20 + 19] = accH[0];   // psi-logit(h_19)
        }
    }

    __syncthreads();

    // ==== epilogue: sigmoid + oxy, 256 threads over 64 sites, guarded ====
    const float wpo = W_p[HDIM];
    if (tid < 64 && base + tid < NSITES) out_psi0[base + tid] = sigmoidf_(psiL[tid * 20]);
    // psi: 64*19 = 1216; out flat i = sl*19 + c <- psiL[sl*20 + c+1]
#pragma unroll
    for (int r = 0; r < 5; ++r) {
        int i = r * 256 + tid;
        if (i < 64 * 19 && (size_t)base * 19 + i < (size_t)NSITES * 19) {
            int s2 = i / 19, c = i - s2 * 19;
            out_psi[(size_t)base * 19 + i] = sigmoidf_(psiL[s2 * 20 + c + 1]);
        }
    }
    // p: 64*40 = 2560 floats = 640 float4; float idx f -> logit pL[f>>1]
    const float4* oxy_b = (const float4*)(oxy + (size_t)base * 40);
    float4* outp_b = (float4*)(out_p + (size_t)base * 40);
    const int p4max = (NSITES * 40) / 4;   // global float4 bound
#pragma unroll
    for (int r = 0; r < 3; ++r) {
        int i4 = r * 256 + tid;
        if (i4 < 640 && blockIdx.x * 640 + i4 < p4max) {
            float4 ox = oxy_b[i4];
            float lg0 = pL[i4 * 2];
            float lg1 = pL[i4 * 2 + 1];
            float4 pv;
            pv.x = sigmoidf_(fmaf(wpo, ox.x, lg0));
            pv.y = sigmoidf_(fmaf(wpo, ox.y, lg0));
            pv.z = sigmoidf_(fmaf(wpo, ox.z, lg1));
            pv.w = sigmoidf_(fmaf(wpo, ox.w, lg1));
            outp_b[i4] = pv;
        }
    }
}

extern "C" void kernel_launch(void* const* d_in, const int* in_sizes, int n_in,
                              void* d_out, int out_size, void* d_ws, size_t ws_size,
                              hipStream_t stream) {
    const float* sxy0   = (const float*)d_in[0];
    const float* sxy    = (const float*)d_in[1];
    const float* oxy    = (const float*)d_in[2];
    const float* W_h0   = (const float*)d_in[3];
    const float* b_h0   = (const float*)d_in[4];
    const float* W_h1   = (const float*)d_in[5];
    const float* b_h1   = (const float*)d_in[6];
    const float* W_ih   = (const float*)d_in[7];
    const float* b_ih   = (const float*)d_in[8];
    const float* W_hh   = (const float*)d_in[9];
    const float* b_hh   = (const float*)d_in[10];
    const float* W_psi0 = (const float*)d_in[11];
    const float* b_psi0 = (const float*)d_in[12];
    const float* W_psi  = (const float*)d_in[13];
    const float* b_psi  = (const float*)d_in[14];
    const float* W_p    = (const float*)d_in[15];
    const float* b_p    = (const float*)d_in[16];

    float* out = (float*)d_out;

    dim3 block(256);
    dim3 grid((NSITES + 63) / 64);   // 1563 blocks, 4 waves x 16 sites each
    rnet_kernel<<<grid, block, 0, stream>>>(
        sxy0, sxy, oxy, W_h0, b_h0, W_h1, b_h1, W_ih, b_ih, W_hh, b_hh,
        W_psi0, b_psi0, W_psi, b_psi, W_p, b_p, out);
}